// Round 5
// baseline (753.624 us; speedup 1.0000x reference)
//
#include <hip/hip_runtime.h>
#include <hip/hip_bf16.h>
#include <math.h>

typedef __bf16 bf16x8 __attribute__((ext_vector_type(8)));
typedef float floatx4 __attribute__((ext_vector_type(4)));

#define T_TOK 4096
#define H_DIM 1024
#define F_DIM 3584
#define E_NUM 8
#define NSLOT 8192  // T_TOK * 2

__device__ __forceinline__ void gload_lds16(const void* g, void* l) {
  __builtin_amdgcn_global_load_lds((const __attribute__((address_space(1))) void*)g,
                                   (__attribute__((address_space(3))) void*)l, 16, 0, 0);
}

__device__ __forceinline__ uint2 pack_bf16x4(float4 v) {
  union {
    unsigned short us[4];
    uint2 u;
  } pk;
  __hip_bfloat16 h0 = __float2bfloat16(v.x);
  __hip_bfloat16 h1 = __float2bfloat16(v.y);
  __hip_bfloat16 h2 = __float2bfloat16(v.z);
  __hip_bfloat16 h3 = __float2bfloat16(v.w);
  pk.us[0] = *(const unsigned short*)&h0;
  pk.us[1] = *(const unsigned short*)&h1;
  pk.us[2] = *(const unsigned short*)&h2;
  pk.us[3] = *(const unsigned short*)&h3;
  return pk.u;
}

// ---------------- K0: cast the three weight tensors fp32 -> bf16, one launch ----------------
__global__ __launch_bounds__(256) void k_cast3(const float* __restrict__ a,
                                               const float* __restrict__ b,
                                               const float* __restrict__ c,
                                               __hip_bfloat16* __restrict__ oa,
                                               __hip_bfloat16* __restrict__ ob,
                                               __hip_bfloat16* __restrict__ oc, int n4) {
  int i = blockIdx.x * 256 + threadIdx.x;
  const float* src;
  __hip_bfloat16* dst;
  if (i < n4) {
    src = a;
    dst = oa;
  } else if (i < 2 * n4) {
    src = b;
    dst = ob;
    i -= n4;
  } else {
    src = c;
    dst = oc;
    i -= 2 * n4;
  }
  float4 v = ((const float4*)src)[i];
  ((uint2*)dst)[i] = pack_bf16x4(v);
}

// ---------------- K1: router (logits, softmax top-2, counts) + fused x cast ----------------
__global__ __launch_bounds__(256) void k_router(const float* __restrict__ x,
                                                const float* __restrict__ gw,
                                                __hip_bfloat16* __restrict__ xb,
                                                int* __restrict__ count,
                                                int* __restrict__ top2e,
                                                float* __restrict__ top2w) {
  const int lane = threadIdx.x & 63;
  const int wv = threadIdx.x >> 6;
  const int t = blockIdx.x * 4 + wv;
  const float4* xv = (const float4*)(x + (size_t)t * H_DIM);
  float4 xa[4];
#pragma unroll
  for (int p = 0; p < 4; ++p) xa[p] = xv[lane + p * 64];
  uint2* xo = (uint2*)(xb + (size_t)t * H_DIM);
#pragma unroll
  for (int p = 0; p < 4; ++p) xo[lane + p * 64] = pack_bf16x4(xa[p]);
  float s[E_NUM];
#pragma unroll
  for (int e = 0; e < E_NUM; ++e) {
    const float4* gv = (const float4*)(gw + e * H_DIM);
    float acc = 0.f;
#pragma unroll
    for (int p = 0; p < 4; ++p) {
      float4 g = gv[lane + p * 64];
      acc += xa[p].x * g.x + xa[p].y * g.y + xa[p].z * g.z + xa[p].w * g.w;
    }
    s[e] = acc;
  }
#pragma unroll
  for (int e = 0; e < E_NUM; ++e) {
#pragma unroll
    for (int m = 32; m; m >>= 1) s[e] += __shfl_xor(s[e], m);
  }
  if (lane == 0) {
    int e0 = 0;
    float l0 = s[0];
    for (int e = 1; e < E_NUM; ++e)
      if (s[e] > l0) { l0 = s[e]; e0 = e; }
    int e1 = (e0 == 0) ? 1 : 0;
    float l1 = s[e1];
    for (int e = 0; e < E_NUM; ++e)
      if (e != e0 && s[e] > l1) { l1 = s[e]; e1 = e; }
    float w0 = 1.f / (1.f + __expf(l1 - l0));
    float w1 = 1.f - w0;
    atomicAdd(&count[e0], 1);
    atomicAdd(&count[e1], 1);
    top2e[2 * t] = e0;
    top2e[2 * t + 1] = e1;
    top2w[2 * t] = w0;
    top2w[2 * t + 1] = w1;
  }
}

// ---------------- K2: exclusive scan of 8 counts ----------------
__global__ void k_scan(const int* __restrict__ count, int* __restrict__ offs) {
  if (threadIdx.x == 0) {
    int a = 0;
    for (int e = 0; e < E_NUM; ++e) { offs[e] = a; a += count[e]; }
  }
}

// ---------------- K3: slot assignment ----------------
__global__ __launch_bounds__(256) void k_assign(const int* __restrict__ top2e,
                                                const float* __restrict__ top2w,
                                                const int* __restrict__ offs,
                                                int* __restrict__ cursor,
                                                int* __restrict__ tok_of_slot,
                                                float* __restrict__ w_of_slot,
                                                int* __restrict__ slot_of_tok) {
  const int t = blockIdx.x * 256 + threadIdx.x;
#pragma unroll
  for (int k = 0; k < 2; ++k) {
    int e = top2e[2 * t + k];
    int pos = atomicAdd(&cursor[e], 1);
    int slot = offs[e] + pos;
    tok_of_slot[slot] = t;
    w_of_slot[slot] = top2w[2 * t + k];
    slot_of_tok[2 * t + k] = slot;
  }
}

// ---------------- K4: grouped GEMM1, 256x256 4-phase schedule ----------------
// BM=256 slots, BN=256 B-rows (w1/w3 interleaved in 16-row groups -> 128 F-cols), BK=64.
// 512 threads = 8 waves (2M x 4N), wave tile 128 slots x 64 B-rows, acc[8][4].
// LDS 2 x 64KB double buffer. Per K-tile: 4 phases {ds_read subtile; stage-issue;
// barrier; 16 MFMA (setprio); barrier}. Tile t+1's 8 loads front-loaded into phases 0-1
// -> at next tile-top vmcnt(0) they had ~2.5 phases (>HBM latency) to land.
__global__ __launch_bounds__(512, 2) void k_gemm1(const __hip_bfloat16* __restrict__ x,
                                                  const __hip_bfloat16* __restrict__ w1,
                                                  const __hip_bfloat16* __restrict__ w3,
                                                  const int* __restrict__ count,
                                                  const int* __restrict__ offs,
                                                  const int* __restrict__ tok_of_slot,
                                                  __hip_bfloat16* __restrict__ hbuf) {
  const int e = blockIdx.z;
  const int Ne = count[e];
  const int mBase = blockIdx.y * 256;
  if (mBase >= Ne) return;
  const int offE = offs[e];
  const int n0 = blockIdx.x * 128;  // F-col panel (128 cols; 256 B-rows w1/w3)
  __shared__ char smem[131072];     // 2 x (A[256][64] 32K | B[256][64] 32K)
  const int tid = threadIdx.x, lane = tid & 63, wv = tid >> 6;
  const int wm = wv >> 2, wn = wv & 3;
  const int chunk = (((tid & 7) ^ ((tid >> 3) & 7)) * 8);  // swizzled source chunk (elems)

  // A sources: 4 sweeps of 64 rows (8 threads/row)
  const __hip_bfloat16* aSrc[4];
#pragma unroll
  for (int j = 0; j < 4; ++j) {
    int rl = j * 64 + (tid >> 3);
    int slot = offE + mBase + rl;
    if (slot > NSLOT - 1) slot = NSLOT - 1;
    int tok = tok_of_slot[slot];
    aSrc[j] = x + (size_t)tok * H_DIM + chunk;
  }
  // B sources: 4 sweeps of 64 rows over 256 B-rows.
  // B-row br: group g=br>>4 (even->w1, odd->w3), F-col = n0 + (br>>5)*16 + (br&15)
  const __hip_bfloat16* bSrc[4];
#pragma unroll
  for (int j = 0; j < 4; ++j) {
    int br = j * 64 + (tid >> 3);
    int f = n0 + ((br >> 5) << 4) + (br & 15);
    const __hip_bfloat16* wsel = ((br >> 4) & 1) ? w3 : w1;
    bSrc[j] = wsel + ((size_t)e * F_DIM + f) * H_DIM + chunk;
  }

  floatx4 acc[8][4];
#pragma unroll
  for (int i = 0; i < 8; ++i)
#pragma unroll
    for (int j = 0; j < 4; ++j) acc[i][j] = (floatx4)0.f;

#define STAGE_A(SB, K0)                                           \
  _Pragma("unroll") for (int j = 0; j < 4; ++j)                   \
      gload_lds16(aSrc[j] + (K0), (SB) + j * 8192 + tid * 16);
#define STAGE_B(SB, K0)                                           \
  _Pragma("unroll") for (int j = 0; j < 4; ++j)                   \
      gload_lds16(bSrc[j] + (K0), (SB) + 32768 + j * 8192 + tid * 16);
#define LD_A(IH, KK)                                                                     \
  _Pragma("unroll") for (int i = 0; i < 4; ++i) {                                        \
    int r = wm * 128 + (IH)*64 + i * 16 + (lane & 15);                                   \
    af[i] = *(const bf16x8*)(sb + r * 128 + ((((KK)*4 + (lane >> 4)) ^ (lane & 7)) * 16)); \
  }
#define LD_B(KK)                                                                         \
  _Pragma("unroll") for (int j = 0; j < 4; ++j) {                                        \
    int r = wn * 64 + j * 16 + (lane & 15);                                              \
    bf[j] = *(const bf16x8*)(sb + 32768 + r * 128 +                                      \
                             ((((KK)*4 + (lane >> 4)) ^ (lane & 7)) * 16));              \
  }
#define MM(IH)                                                                           \
  __builtin_amdgcn_s_setprio(1);                                                         \
  _Pragma("unroll") for (int i = 0; i < 4; ++i)                                          \
  _Pragma("unroll") for (int j = 0; j < 4; ++j)                                          \
      acc[(IH)*4 + i][j] =                                                               \
          __builtin_amdgcn_mfma_f32_16x16x32_bf16(af[i], bf[j], acc[(IH)*4 + i][j], 0, 0, 0); \
  __builtin_amdgcn_s_setprio(0);

  const int NT = H_DIM / 64;  // 16
  STAGE_A(smem, 0);
  STAGE_B(smem, 0);
  for (int t = 0; t < NT; ++t) {
    const char* sb = smem + (t & 1) * 65536;
    char* nb = smem + ((t + 1) & 1) * 65536;
    const int kn = (t + 1) * 64;
    asm volatile("s_waitcnt vmcnt(0)" ::: "memory");  // tile t landed (issued ~2.5 phases ago)
    __builtin_amdgcn_s_barrier();
    __builtin_amdgcn_sched_barrier(0);
    bf16x8 af[4], bf[4];
    // phase 0: kk=0, i-half 0; stage A of tile t+1
    LD_A(0, 0);
    LD_B(0);
    if (t + 1 < NT) { STAGE_A(nb, kn); }
    __builtin_amdgcn_s_barrier();
    MM(0);
    __builtin_amdgcn_s_barrier();
    // phase 1: kk=0, i-half 1 (bf reused); stage B of tile t+1
    LD_A(1, 0);
    if (t + 1 < NT) { STAGE_B(nb, kn); }
    __builtin_amdgcn_s_barrier();
    MM(1);
    __builtin_amdgcn_s_barrier();
    // phase 2: kk=1, i-half 0
    LD_A(0, 1);
    LD_B(1);
    __builtin_amdgcn_s_barrier();
    MM(0);
    __builtin_amdgcn_s_barrier();
    // phase 3: kk=1, i-half 1
    LD_A(1, 1);
    __builtin_amdgcn_s_barrier();
    MM(1);
    __builtin_amdgcn_s_barrier();
  }
#undef STAGE_A
#undef STAGE_B
#undef LD_A
#undef LD_B
#undef MM

  // epilogue: acc[a][*], a = ih*4+i -> A-row = wm*128 + (a>>2)*64 + (a&3)*16.
  // j pairs: (0,1)=(w1,w3)@col c0, (2,3)@c0+16, c0 = n0 + wn*32 + (lane&15)
#pragma unroll
  for (int a = 0; a < 8; ++a)
#pragma unroll
    for (int reg = 0; reg < 4; ++reg) {
      int rl = wm * 128 + (a >> 2) * 64 + (a & 3) * 16 + (lane >> 4) * 4 + reg;
      int rg = mBase + rl;
      if (rg < Ne) {
        size_t slot = (size_t)offE + rg;
        int c0 = n0 + wn * 32 + (lane & 15);
        float v1 = acc[a][0][reg], v3 = acc[a][1][reg];
        hbuf[slot * F_DIM + c0] = __float2bfloat16(v1 / (1.f + __expf(-v1)) * v3);
        float u1 = acc[a][2][reg], u3 = acc[a][3][reg];
        hbuf[slot * F_DIM + c0 + 16] = __float2bfloat16(u1 / (1.f + __expf(-u1)) * u3);
      }
    }
}

// ---------------- K5: grouped GEMM2 (h @ w2^T, scaled, fused combine via atomicAdd) ----------------
// R4-proven structure, unchanged.
__global__ __launch_bounds__(256) void k_gemm2(const __hip_bfloat16* __restrict__ hbuf,
                                               const __hip_bfloat16* __restrict__ w2,
                                               const int* __restrict__ count,
                                               const int* __restrict__ offs,
                                               const float* __restrict__ w_of_slot,
                                               const int* __restrict__ tok_of_slot,
                                               float* __restrict__ out) {
  const int lin = blockIdx.x + 16 * blockIdx.y + 512 * blockIdx.z;
  const int wg = (lin & 7) * 512 + (lin >> 3);
  const int xb = wg & 15;
  const int yb = (wg >> 4) & 31;
  const int e = wg >> 9;
  const int Ne = count[e];
  const int mBase = yb * 128;
  if (mBase >= Ne) return;
  const int offE = offs[e];
  const int n0 = xb * 64;
  __shared__ char smem[24576];  // A 16K | B 8K
  const int tid = threadIdx.x, lane = tid & 63, wv = tid >> 6;
  const int wm = wv >> 1, wn = wv & 1;
  const int srcOff = ((lane & 7) ^ (lane >> 3)) * 8;

  const __hip_bfloat16* aSrc[4];
#pragma unroll
  for (int j = 0; j < 4; ++j) {
    int rl = wv * 32 + j * 8 + (lane >> 3);
    int slot = offE + mBase + rl;
    if (slot > NSLOT - 1) slot = NSLOT - 1;
    aSrc[j] = hbuf + (size_t)slot * F_DIM + srcOff;
  }
  const __hip_bfloat16* bSrc[2];
#pragma unroll
  for (int j = 0; j < 2; ++j) {
    int rl = wv * 16 + j * 8 + (lane >> 3);
    bSrc[j] = w2 + ((size_t)e * H_DIM + n0 + rl) * F_DIM + srcOff;
  }

  floatx4 acc[4][2];
#pragma unroll
  for (int i = 0; i < 4; ++i)
#pragma unroll
    for (int j = 0; j < 2; ++j) acc[i][j] = (floatx4)0.f;

  for (int kt = 0; kt < F_DIM / 64; ++kt) {
    const int k0 = kt * 64;
#pragma unroll
    for (int j = 0; j < 4; ++j)
      gload_lds16(aSrc[j] + k0, smem + wv * 4096 + j * 1024 + lane * 16);
#pragma unroll
    for (int j = 0; j < 2; ++j)
      gload_lds16(bSrc[j] + k0, smem + 16384 + wv * 2048 + j * 1024 + lane * 16);
    __syncthreads();
#pragma unroll
    for (int kk = 0; kk < 2; ++kk) {
      bf16x8 af[4], bf[2];
      const int posx = ((kk * 4 + (lane >> 4)) ^ (lane & 7)) * 16;
#pragma unroll
      for (int i = 0; i < 4; ++i) {
        int r = wm * 64 + i * 16 + (lane & 15);
        af[i] = *(const bf16x8*)(smem + r * 128 + posx);
      }
#pragma unroll
      for (int j = 0; j < 2; ++j) {
        int r = wn * 32 + j * 16 + (lane & 15);
        bf[j] = *(const bf16x8*)(smem + 16384 + r * 128 + posx);
      }
#pragma unroll
      for (int i = 0; i < 4; ++i)
#pragma unroll
        for (int j = 0; j < 2; ++j)
          acc[i][j] = __builtin_amdgcn_mfma_f32_16x16x32_bf16(af[i], bf[j], acc[i][j], 0, 0, 0);
    }
    __syncthreads();
  }
#pragma unroll
  for (int i = 0; i < 4; ++i)
#pragma unroll
    for (int reg = 0; reg < 4; ++reg) {
      int rl = wm * 64 + i * 16 + (lane >> 4) * 4 + reg;
      int rg = mBase + rl;
      if (rg < Ne) {
        size_t slot = (size_t)offE + rg;
        float wt = w_of_slot[slot];
        int tok = tok_of_slot[slot];
#pragma unroll
        for (int j = 0; j < 2; ++j) {
          int col = n0 + wn * 32 + j * 16 + (lane & 15);
          atomicAdd(out + (size_t)tok * H_DIM + col, acc[i][j][reg] * wt);
        }
      }
    }
}

extern "C" void kernel_launch(void* const* d_in, const int* in_sizes, int n_in,
                              void* d_out, int out_size, void* d_ws, size_t ws_size,
                              hipStream_t stream) {
  const float* x = (const float*)d_in[0];
  const float* gw = (const float*)d_in[1];
  const float* w1 = (const float*)d_in[2];
  const float* w2 = (const float*)d_in[3];
  const float* w3 = (const float*)d_in[4];
  float* out = (float*)d_out;

  char* ws = (char*)d_ws;
  int* count = (int*)(ws + 0);     // 8 ints
  int* cursor = (int*)(ws + 256);  // 8 ints
  int* offs = (int*)(ws + 512);    // 8 ints
  int* top2e = (int*)(ws + 4096);
  float* top2w = (float*)(ws + 4096 + 32768);
  int* tok_of_slot = (int*)(ws + 4096 + 65536);
  float* w_of_slot = (float*)(ws + 4096 + 98304);
  int* slot_of_tok = (int*)(ws + 4096 + 131072);
  char* big = ws + 167936;
  __hip_bfloat16* xb = (__hip_bfloat16*)(big);                   // 8 MB
  __hip_bfloat16* w1b = (__hip_bfloat16*)(big + 8388608);        // 58.7 MB
  __hip_bfloat16* w3b = (__hip_bfloat16*)(big + 67108864ULL);    // 58.7 MB
  __hip_bfloat16* w2b = (__hip_bfloat16*)(big + 125829120ULL);   // 58.7 MB
  __hip_bfloat16* hbuf = (__hip_bfloat16*)(big + 184549376ULL);  // 58.7 MB

  const int n4_w = (E_NUM * F_DIM * H_DIM) / 4;  // 7340032

  hipMemsetAsync(ws, 0, 512, stream);  // zero count + cursor
  hipMemsetAsync(out, 0, (size_t)T_TOK * H_DIM * 4, stream);  // accumulate target
  k_cast3<<<3 * n4_w / 256, 256, 0, stream>>>(w1, w2, w3, w1b, w2b, w3b, n4_w);
  k_router<<<T_TOK / 4, 256, 0, stream>>>(x, gw, xb, count, top2e, top2w);
  k_scan<<<1, 64, 0, stream>>>(count, offs);
  k_assign<<<T_TOK / 256, 256, 0, stream>>>(top2e, top2w, offs, cursor, tok_of_slot,
                                            w_of_slot, slot_of_tok);
  dim3 g1(F_DIM / 128, T_TOK / 256, E_NUM);
  k_gemm1<<<g1, 512, 0, stream>>>(xb, w1b, w3b, count, offs, tok_of_slot, hbuf);
  dim3 g2(H_DIM / 64, T_TOK / 128, E_NUM);
  k_gemm2<<<g2, 256, 0, stream>>>(hbuf, w2b, count, offs, w_of_slot, tok_of_slot, out);
}